// Round 12
// baseline (1419.658 us; speedup 1.0000x reference)
//
#include <hip/hip_runtime.h>

// AttnDecoderRNN: B=64, S=128, T=32, H=1024, V=32000
// out = [log_probs (B,T,V) | h_final (1,B,H) | attentions (B,T,S)], all f32.

typedef unsigned short u16;
typedef __bf16 bf16x8 __attribute__((ext_vector_type(8)));
typedef float f32x4 __attribute__((ext_vector_type(4)));
typedef u16 u16x8 __attribute__((ext_vector_type(8)));

#define DEV __device__ __forceinline__

DEV u16 f2b(float f) {               // f32 -> bf16 RNE
  union { float f; unsigned u; } v; v.f = f;
  unsigned r = v.u + 0x7fffu + ((v.u >> 16) & 1u);
  return (u16)(r >> 16);
}
DEV float b2f(u16 b) {
  union { unsigned u; float f; } v; v.u = ((unsigned)b) << 16;
  return v.f;
}
DEV float sigm(float x) { return 1.f / (1.f + __expf(-x)); }
DEV float ftanh(float x) {
  x = fminf(fmaxf(x, -20.f), 20.f);
  float e = __expf(2.f * x);
  return (e - 1.f) / (e + 1.f);
}
DEV void gl16(const void* g, void* l) {  // 16B global -> LDS direct (wave-uniform lds base, +lane*16)
  __builtin_amdgcn_global_load_lds((const __attribute__((address_space(1))) void*)g,
                                   (__attribute__((address_space(3))) void*)l, 16, 0, 0);
}

// ---------- single prep kernel: all conversions + Wih split + emb gather + h init ----------
__global__ __launch_bounds__(256) void prepk(const float* __restrict__ enc, const float* __restrict__ Ua,
                                             const float* __restrict__ Wa, const float* __restrict__ Whh,
                                             const float* __restrict__ Wout, const float* __restrict__ Wih,
                                             const float* __restrict__ embd, const int* __restrict__ tgt,
                                             const float* __restrict__ eh, u16* __restrict__ enc_b,
                                             u16* __restrict__ Ua_b, u16* __restrict__ Wa_b,
                                             u16* __restrict__ Whh_b, u16* __restrict__ Wout_b,
                                             u16* __restrict__ Wih1_b, u16* __restrict__ Wih2_b,
                                             u16* __restrict__ emb_b, float* __restrict__ hf,
                                             u16* __restrict__ hb0) {
  const long q0 = 2097152;            // enc        64*128*1024/4
  const long q1 = q0 + 262144;        // Ua         1024*1024/4
  const long q2 = q1 + 262144;        // Wa
  const long q3 = q2 + 786432;        // Whh        3072*1024/4
  const long q4 = q3 + 8192000;       // Wout       32000*1024/4
  const long q5 = q4 + 1572864;       // Wih split  3072*2048/4
  const long q6 = q5 + 524288;        // emb gather 64*32*1024/4
  const long q7 = q6 + 16384;         // h init     64*1024/4
  long stride = (long)gridDim.x * 256;
  for (long i = (long)blockIdx.x * 256 + threadIdx.x; i < q7; i += stride) {
    if (i < q4) {  // plain f32 -> bf16 copies
      const float* src; u16* dst; long off;
      if (i < q0) { src = enc; dst = enc_b; off = i; }
      else if (i < q1) { src = Ua; dst = Ua_b; off = i - q0; }
      else if (i < q2) { src = Wa; dst = Wa_b; off = i - q1; }
      else if (i < q3) { src = Whh; dst = Whh_b; off = i - q2; }
      else { src = Wout; dst = Wout_b; off = i - q3; }
      float4 v = ((const float4*)src)[off];
      ushort4 o; o.x = f2b(v.x); o.y = f2b(v.y); o.z = f2b(v.z); o.w = f2b(v.w);
      ((ushort4*)dst)[off] = o;
    } else if (i < q5) {  // Wih (3072x2048) -> Wih1 | Wih2
      long off = i - q4;
      long e = off * 4;
      int row = (int)(e >> 11), col = (int)(e & 2047);
      float4 v = ((const float4*)Wih)[off];
      ushort4 o; o.x = f2b(v.x); o.y = f2b(v.y); o.z = f2b(v.z); o.w = f2b(v.w);
      u16* dst = (col < 1024) ? (Wih1_b + (size_t)row * 1024 + col)
                              : (Wih2_b + (size_t)row * 1024 + col - 1024);
      *(ushort4*)dst = o;
    } else if (i < q6) {  // embedding gather (SOS=1 teacher forcing)
      long off = i - q5;
      size_t e = (size_t)off * 4;
      int h = (int)(e & 1023);
      int bt = (int)(e >> 10);
      int b = bt >> 5, t = bt & 31;
      int tok = (t == 0) ? 1 : tgt[b * 32 + t - 1];
      const float* src = embd + (size_t)tok * 1024 + h;
      float4 v = *(const float4*)src;
      ushort4 o; o.x = f2b(v.x); o.y = f2b(v.y); o.z = f2b(v.z); o.w = f2b(v.w);
      *(ushort4*)(emb_b + e) = o;
    } else {  // h init: f32 copy + bf16 copy
      long off = i - q6;
      float4 v = ((const float4*)eh)[off];
      ((float4*)hf)[off] = v;
      ushort4 o; o.x = f2b(v.x); o.y = f2b(v.y); o.z = f2b(v.z); o.w = f2b(v.w);
      ((ushort4*)hb0)[off] = o;
    }
  }
}

// ---------- 128x128-tile bf16 MFMA GEMM (NT: A MxK, B NxK, both K-contig) ----------
// Staging: 4 lanes per row (64B contiguous) + XOR chunk swizzle within the row's 64B
//   (source chunk = (lane&3) ^ ((row>>1)&3)) -> coalescing preserved, LDS read conflict-free.
// MODE 0: f32 C=acc+bias. MODE 1: bf16 C=acc+bias. MODE 2: bf16 C=acc (no bias).
template <int MODE>
__global__ __launch_bounds__(256) void gemm_tile(const u16* __restrict__ A, const u16* __restrict__ Bm,
                                                 const float* __restrict__ bias, float* __restrict__ Cf,
                                                 u16* __restrict__ Cb, int K, int ldc, int nTM) {
  __shared__ __attribute__((aligned(16))) u16 As[128 * 32];
  __shared__ __attribute__((aligned(16))) u16 Bs[128 * 32];
  const int tid = threadIdx.x, lane = tid & 63, w = tid >> 6;
  const int chunk = gridDim.x >> 3, wg = blockIdx.x;
  const int id = (wg & 7) * chunk + (wg >> 3);
  const int m = id % nTM, n = id / nTM;
  const int m0 = m * 128, n0 = n * 128;
  const int wm = w >> 1, wn = w & 1;
  const int l16 = lane & 15, kg = lane >> 4;
  const int srow = lane >> 2;
  const int skk = (((lane & 3) ^ ((srow >> 1) & 3)) * 8);
  const int slot = (kg ^ ((l16 >> 1) & 3)) * 8;

  f32x4 acc[4][4];
#pragma unroll
  for (int i = 0; i < 4; ++i)
#pragma unroll
    for (int j = 0; j < 4; ++j) acc[i][j] = f32x4{0.f, 0.f, 0.f, 0.f};

  for (int k0 = 0; k0 < K; k0 += 32) {
#pragma unroll
    for (int ch = 0; ch < 2; ++ch) {
      int c = w + ch * 4;
      gl16(A + (size_t)(m0 + c * 16 + srow) * K + k0 + skk, &As[c * 512]);
      gl16(Bm + (size_t)(n0 + c * 16 + srow) * K + k0 + skk, &Bs[c * 512]);
    }
    __syncthreads();
    bf16x8 av[4], bv[4];
#pragma unroll
    for (int i = 0; i < 4; ++i) av[i] = *(const bf16x8*)&As[(wm * 4 + i) * 512 + l16 * 32 + slot];
#pragma unroll
    for (int j = 0; j < 4; ++j) bv[j] = *(const bf16x8*)&Bs[(wn * 4 + j) * 512 + l16 * 32 + slot];
#pragma unroll
    for (int i = 0; i < 4; ++i)
#pragma unroll
      for (int j = 0; j < 4; ++j)
        acc[i][j] = __builtin_amdgcn_mfma_f32_16x16x32_bf16(av[i], bv[j], acc[i][j], 0, 0, 0);
    __syncthreads();
  }
#pragma unroll
  for (int i = 0; i < 4; ++i) {
    int rowb = m0 + (wm * 4 + i) * 16 + kg * 4;
#pragma unroll
    for (int j = 0; j < 4; ++j) {
      int col = n0 + (wn * 4 + j) * 16 + l16;
      float bb = (MODE == 2) ? 0.f : bias[col];
#pragma unroll
      for (int r = 0; r < 4; ++r) {
        int row = rowb + r;
        float v = acc[i][j][r] + bb;
        if (MODE == 0) Cf[(size_t)row * ldc + col] = v;
        else Cb[(size_t)row * ldc + col] = f2b(v);
      }
    }
  }
}

// ---------- 128x256-tile bf16 MFMA GEMM, BK=64 (2 panels of 32 per K-step) ----------
// Same verified staging/swizzle per 32-panel; barrier count halved vs BK=32.
// MODE 0: f32+bias, logits row remap. MODE 1: bf16+bias, logits row remap.
// MODE 2: bf16, no bias, plain row-major write (encW2).
// MAP 0: logits 16m x 125n with 80-id supertiles. MAP 1: m = id % nTM, n = id / nTM.
template <int MODE, int MAP>
__global__ __launch_bounds__(256, 2) void gemm_wide(const u16* __restrict__ A, const u16* __restrict__ Bm,
                                                    const float* __restrict__ bias, float* __restrict__ Cf,
                                                    u16* __restrict__ Cb, int K, int ldc, int nTM) {
  __shared__ __attribute__((aligned(16))) u16 As[128 * 64];   // 16 KB
  __shared__ __attribute__((aligned(16))) u16 Bs[256 * 64];   // 32 KB
  const int tid = threadIdx.x, lane = tid & 63, w = tid >> 6;
  const int chunk = gridDim.x >> 3, wg = blockIdx.x;
  const int id = (wg & 7) * chunk + (wg >> 3);
  int m, n;
  if (MAP == 0) { int r_ = id % 80; m = r_ & 15; n = 5 * (id / 80) + (r_ >> 4); }
  else { m = id % nTM; n = id / nTM; }
  const int m0 = m * 128, n0 = n * 256;
  const int wm = w >> 1, wn = w & 1;
  const int l16 = lane & 15, kg = lane >> 4;
  const int srow = lane >> 2;
  const int skk = (((lane & 3) ^ ((srow >> 1) & 3)) * 8);
  const int slot = (kg ^ ((l16 >> 1) & 3)) * 8;

  f32x4 acc[4][8];
#pragma unroll
  for (int i = 0; i < 4; ++i)
#pragma unroll
    for (int j = 0; j < 8; ++j) acc[i][j] = f32x4{0.f, 0.f, 0.f, 0.f};

  for (int k0 = 0; k0 < K; k0 += 64) {
#pragma unroll
    for (int ch = 0; ch < 2; ++ch) {
      int c = w + ch * 4;  // A: 8 chunks of 16 rows, 2 panels each
#pragma unroll
      for (int p = 0; p < 2; ++p)
        gl16(A + (size_t)(m0 + c * 16 + srow) * K + k0 + p * 32 + skk, &As[c * 1024 + p * 512]);
    }
#pragma unroll
    for (int ch = 0; ch < 4; ++ch) {
      int c = w + ch * 4;  // B: 16 chunks of 16 rows, 2 panels each
#pragma unroll
      for (int p = 0; p < 2; ++p)
        gl16(Bm + (size_t)(n0 + c * 16 + srow) * K + k0 + p * 32 + skk, &Bs[c * 1024 + p * 512]);
    }
    __syncthreads();
#pragma unroll
    for (int p = 0; p < 2; ++p) {
      bf16x8 av[4], bv[8];
#pragma unroll
      for (int i = 0; i < 4; ++i)
        av[i] = *(const bf16x8*)&As[(wm * 4 + i) * 1024 + p * 512 + l16 * 32 + slot];
#pragma unroll
      for (int j = 0; j < 8; ++j)
        bv[j] = *(const bf16x8*)&Bs[(wn * 8 + j) * 1024 + p * 512 + l16 * 32 + slot];
#pragma unroll
      for (int i = 0; i < 4; ++i)
#pragma unroll
        for (int j = 0; j < 8; ++j)
          acc[i][j] = __builtin_amdgcn_mfma_f32_16x16x32_bf16(av[i], bv[j], acc[i][j], 0, 0, 0);
    }
    __syncthreads();
  }
#pragma unroll
  for (int i = 0; i < 4; ++i) {
    int rowb = m0 + (wm * 4 + i) * 16 + kg * 4;
#pragma unroll
    for (int j = 0; j < 8; ++j) {
      int col = n0 + (wn * 8 + j) * 16 + l16;
      float bb = (MODE == 2) ? 0.f : bias[col];
#pragma unroll
      for (int r = 0; r < 4; ++r) {
        int row = rowb + r;
        float v = acc[i][j][r] + bb;
        if (MODE == 2) {
          Cb[(size_t)row * ldc + col] = f2b(v);
        } else {
          int b_ = row & 63, t_ = row >> 6;  // hall rows are (t*64+b)
          size_t ro = ((size_t)b_ * 32 + t_) * ldc + col;
          if (MODE == 0) Cf[ro] = v; else Cb[ro] = f2b(v);
        }
      }
    }
  }
}

// ---------- per-step K1: qgh partials = h @ [Wa;Whh]^T, K split by 4. grid 1024 ----------
__global__ __launch_bounds__(256) void qkghk(const u16* __restrict__ hb, const u16* __restrict__ W1,
                                             float* __restrict__ qghp) {
  const int tid = threadIdx.x, lane = tid & 63, w = tid >> 6;
  const int l16 = lane & 15, kg = lane >> 4;
  const int pg = blockIdx.x >> 2, ks = blockIdx.x & 3;
  const u16* ap = hb + (size_t)(w * 16 + l16) * 1024 + ks * 256 + kg * 8;
  const u16* bp = W1 + (size_t)(pg * 16 + l16) * 1024 + ks * 256 + kg * 8;
  f32x4 a = {0.f, 0.f, 0.f, 0.f};
#pragma unroll
  for (int k0 = 0; k0 < 256; k0 += 32)
    a = __builtin_amdgcn_mfma_f32_16x16x32_bf16(*(const bf16x8*)(ap + k0), *(const bf16x8*)(bp + k0),
                                                a, 0, 0, 0);
  const int col = pg * 16 + l16;
#pragma unroll
  for (int r = 0; r < 4; ++r) {
    int b = w * 16 + kg * 4 + r;
    qghp[(size_t)ks * 262144 + b * 4096 + col] = a[r];
  }
}

// ---------- per-step K2: scores. grid 512 = (b 64) x (s-eighth 8); 4 scores/wave ----------
__global__ __launch_bounds__(256) void scorekq(const float* __restrict__ qghp, const float* __restrict__ ba,
                                               const float* __restrict__ Va, const u16* __restrict__ kp,
                                               float* __restrict__ sc) {
  const int b = blockIdx.x >> 3, s8 = blockIdx.x & 7;
  const int tid = threadIdx.x, lane = tid & 63, w = tid >> 6;
  __shared__ float qs[1024], vas[1024];
#pragma unroll
  for (int j = 0; j < 4; ++j) {
    int e = tid + j * 256;
    qs[e] = qghp[b * 4096 + e] + qghp[262144 + b * 4096 + e] + qghp[524288 + b * 4096 + e] +
            qghp[786432 + b * 4096 + e] + ba[e];
    vas[e] = Va[e];
  }
  __syncthreads();
#pragma unroll
  for (int si = 0; si < 4; ++si) {
    int s = s8 * 16 + w * 4 + si;
    const bf16x8* kv = (const bf16x8*)(kp + ((size_t)b * 128 + s) * 1024);
    float a = 0.f;
#pragma unroll
    for (int i2 = 0; i2 < 2; ++i2) {
      int e = lane + 64 * i2;
      bf16x8 k8 = kv[e];
#pragma unroll
      for (int j = 0; j < 8; ++j) a += vas[e * 8 + j] * ftanh(qs[e * 8 + j] + (float)k8[j]);
    }
#pragma unroll
    for (int off = 32; off; off >>= 1) a += __shfl_xor(a, off);
    if (lane == 0) sc[b * 128 + s] = a;  // +bv cancels in softmax
  }
}

// ---------- per-step K3: softmax + encW2 weighted sum (col-vectorized) + GRU gates ----------
// grid 256 = (b 64) x (col-quarter 4), 512 threads = 32 col-groups (8 cols, u16x8 loads)
// x 16 s-groups (8 s each). Partials via LDS pa[16][3][256]; gates tail (tid<256) verbatim.
__global__ __launch_bounds__(512) void wsumgate(const float* __restrict__ scb, const u16* __restrict__ encW2,
                                                const float* __restrict__ gie, const float* __restrict__ qghp,
                                                const float* __restrict__ bhh, float* __restrict__ hf,
                                                u16* __restrict__ hbW, u16* __restrict__ hall,
                                                float* __restrict__ hfin, float* __restrict__ att_out, int t) {
  const int b = blockIdx.x >> 2, cg = blockIdx.x & 3;
  const int tid = threadIdx.x, lane = tid & 63, w = tid >> 6;
  __shared__ float wsm[128];
  __shared__ float pa[16][3][256];
  if (w == 0) {  // softmax over 128 scores (verified pattern)
    float v0 = scb[b * 128 + lane], v1 = scb[b * 128 + 64 + lane];
    float mx = fmaxf(v0, v1);
#pragma unroll
    for (int off = 32; off; off >>= 1) mx = fmaxf(mx, __shfl_xor(mx, off));
    float e0 = __expf(v0 - mx), e1 = __expf(v1 - mx);
    float sm = e0 + e1;
#pragma unroll
    for (int off = 32; off; off >>= 1) sm += __shfl_xor(sm, off);
    float inv = 1.f / sm;
    e0 *= inv; e1 *= inv;
    wsm[lane] = e0; wsm[lane + 64] = e1;
    if (cg == 0) {
      size_t ao = ((size_t)b * 32 + t) * 128;
      att_out[ao + lane] = e0;
      att_out[ao + lane + 64] = e1;
    }
  }
  __syncthreads();
  const int cg8 = tid & 31, sg = tid >> 5;    // col-group (8 cols), s-group (8 s)
  const int colBase = cg * 256 + cg8 * 8;
  float a0[8], a1[8], a2[8];
#pragma unroll
  for (int k = 0; k < 8; ++k) { a0[k] = 0.f; a1[k] = 0.f; a2[k] = 0.f; }
  const u16* ep = encW2 + ((size_t)b * 128 + sg * 8) * 3072 + colBase;
#pragma unroll
  for (int si = 0; si < 8; ++si) {
    float ws = wsm[sg * 8 + si];
    u16x8 v0 = *(const u16x8*)(ep);
    u16x8 v1 = *(const u16x8*)(ep + 1024);
    u16x8 v2 = *(const u16x8*)(ep + 2048);
#pragma unroll
    for (int k = 0; k < 8; ++k) {
      a0[k] += ws * b2f(v0[k]);
      a1[k] += ws * b2f(v1[k]);
      a2[k] += ws * b2f(v2[k]);
    }
    ep += 3072;
  }
  {
    f32x4 t0 = {a0[0], a0[1], a0[2], a0[3]}, t1 = {a0[4], a0[5], a0[6], a0[7]};
    *(f32x4*)&pa[sg][0][cg8 * 8] = t0; *(f32x4*)&pa[sg][0][cg8 * 8 + 4] = t1;
    f32x4 t2 = {a1[0], a1[1], a1[2], a1[3]}, t3 = {a1[4], a1[5], a1[6], a1[7]};
    *(f32x4*)&pa[sg][1][cg8 * 8] = t2; *(f32x4*)&pa[sg][1][cg8 * 8 + 4] = t3;
    f32x4 t4 = {a2[0], a2[1], a2[2], a2[3]}, t5 = {a2[4], a2[5], a2[6], a2[7]};
    *(f32x4*)&pa[sg][2][cg8 * 8] = t4; *(f32x4*)&pa[sg][2][cg8 * 8 + 4] = t5;
  }
  __syncthreads();
  if (tid < 256) {
    float g0 = 0.f, g1 = 0.f, g2 = 0.f;
#pragma unroll
    for (int s2 = 0; s2 < 16; ++s2) {
      g0 += pa[s2][0][tid]; g1 += pa[s2][1][tid]; g2 += pa[s2][2][tid];
    }
    const int c2 = cg * 256 + tid;
    const float* ge = gie + ((size_t)b * 32 + t) * 3072 + c2;   // emb part of gi (+b_ih)
    const float* qg = qghp + (size_t)b * 4096 + 1024 + c2;      // gh partials (W1 rows 1024+)
    float hr = qg[0] + qg[262144] + qg[524288] + qg[786432] + bhh[c2];
    float hz = qg[1024] + qg[1024 + 262144] + qg[1024 + 524288] + qg[1024 + 786432] + bhh[c2 + 1024];
    float hn = qg[2048] + qg[2048 + 262144] + qg[2048 + 524288] + qg[2048 + 786432] + bhh[c2 + 2048];
    float rr = sigm(g0 + ge[0] + hr);
    float zz = sigm(g1 + ge[1024] + hz);
    float nn = ftanh(g2 + ge[2048] + rr * hn);
    const int i = b * 1024 + c2;
    float hp = hf[i];
    float hv = (1.f - zz) * nn + zz * hp;
    hf[i] = hv;
    u16 h16 = f2b(hv);
    hbW[i] = h16;
    hall[((size_t)t * 64 + b) * 1024 + c2] = h16;
    if (t == 31) hfin[i] = hv;
  }
}

// ---------- fallback per-step kernels (used only when encW2 does not fit in ws) ----------
__global__ __launch_bounds__(256) void smaxctxk(const float* __restrict__ sc, const u16* __restrict__ encb,
                                                u16* __restrict__ ctxb, float* __restrict__ att_out, int t) {
  const int b = blockIdx.x >> 2, hq = blockIdx.x & 3;
  const int tid = threadIdx.x, lane = tid & 63, w = tid >> 6;
  __shared__ float wsm[128];
  if (w == 0) {
    float v0 = sc[b * 128 + lane], v1 = sc[b * 128 + 64 + lane];
    float mx = fmaxf(v0, v1);
#pragma unroll
    for (int off = 32; off; off >>= 1) mx = fmaxf(mx, __shfl_xor(mx, off));
    float e0 = __expf(v0 - mx), e1 = __expf(v1 - mx);
    float sm = e0 + e1;
#pragma unroll
    for (int off = 32; off; off >>= 1) sm += __shfl_xor(sm, off);
    float inv = 1.f / sm;
    e0 *= inv; e1 *= inv;
    wsm[lane] = e0; wsm[lane + 64] = e1;
    if (hq == 0) {
      size_t ao = ((size_t)b * 32 + t) * 128;
      att_out[ao + lane] = e0;
      att_out[ao + lane + 64] = e1;
    }
  }
  __syncthreads();
  const int h = hq * 256 + tid;
  const u16* ep = encb + (size_t)b * 131072 + h;
  float c = 0.f;
#pragma unroll 8
  for (int s = 0; s < 128; ++s) c += wsm[s] * b2f(ep[(size_t)s * 1024]);
  ctxb[(size_t)b * 1024 + h] = f2b(c);
}

__global__ __launch_bounds__(256) void gi2w(const u16* __restrict__ ctxb, const u16* __restrict__ Wih2,
                                            float* __restrict__ gic) {
  const int tid = threadIdx.x, lane = tid & 63, w = tid >> 6;
  const int l16 = lane & 15, kg = lane >> 4;
  const int c0 = blockIdx.x * 16;  // grid 192
  const u16* ap = ctxb + (size_t)(w * 16 + l16) * 1024 + kg * 8;
  const u16* bp = Wih2 + (size_t)(c0 + l16) * 1024 + kg * 8;
  f32x4 a0 = {0.f, 0.f, 0.f, 0.f}, a1 = {0.f, 0.f, 0.f, 0.f};
#pragma unroll 4
  for (int k0 = 0; k0 < 1024; k0 += 64) {
    a0 = __builtin_amdgcn_mfma_f32_16x16x32_bf16(*(const bf16x8*)(ap + k0), *(const bf16x8*)(bp + k0),
                                                 a0, 0, 0, 0);
    a1 = __builtin_amdgcn_mfma_f32_16x16x32_bf16(*(const bf16x8*)(ap + k0 + 32),
                                                 *(const bf16x8*)(bp + k0 + 32), a1, 0, 0, 0);
  }
  const int col = c0 + l16;
#pragma unroll
  for (int r = 0; r < 4; ++r) {
    int b = w * 16 + kg * 4 + r;
    gic[(size_t)b * 3072 + col] = a0[r] + a1[r];
  }
}

__global__ __launch_bounds__(256) void gatesq(const float* __restrict__ gic, const float* __restrict__ gie,
                                              const float* __restrict__ qghp, const float* __restrict__ bhh,
                                              float* __restrict__ hf, u16* __restrict__ hbW,
                                              u16* __restrict__ hall, float* __restrict__ hfin, int t) {
  const int i = blockIdx.x * 256 + threadIdx.x;  // 65536 = (b, col)
  const int b = i >> 10, col = i & 1023;
  const float* gi = gic + (size_t)b * 3072 + col;
  const float* ge = gie + ((size_t)b * 32 + t) * 3072 + col;
  const float* qg = qghp + (size_t)b * 4096 + 1024 + col;
  float hr = qg[0] + qg[262144] + qg[524288] + qg[786432] + bhh[col];
  float hz = qg[1024] + qg[1024 + 262144] + qg[1024 + 524288] + qg[1024 + 786432] + bhh[col + 1024];
  float hn = qg[2048] + qg[2048 + 262144] + qg[2048 + 524288] + qg[2048 + 786432] + bhh[col + 2048];
  float rr = sigm(gi[0] + ge[0] + hr);
  float zz = sigm(gi[1024] + ge[1024] + hz);
  float nn = ftanh(gi[2048] + ge[2048] + rr * hn);
  float hp = hf[i];
  float hv = (1.f - zz) * nn + zz * hp;
  hf[i] = hv;
  u16 h16 = f2b(hv);
  hbW[i] = h16;
  hall[((size_t)t * 64 + b) * 1024 + col] = h16;
  if (t == 31) hfin[i] = hv;
}

// ---------- fused log_softmax over bf16 logits ----------
__global__ __launch_bounds__(256) void logsoftk(const u16* __restrict__ lg, float* __restrict__ out) {
  const int row = blockIdx.x, tid = threadIdx.x, lane = tid & 63, w = tid >> 6;
  const u16x8* p = (const u16x8*)(lg + (size_t)row * 32000);
  __shared__ float red[4];
  u16x8 d[16];
#pragma unroll
  for (int j = 0; j < 16; ++j) {
    int i = tid + j * 256;
    if (i < 4000) d[j] = p[i];
  }
  float mx = -3.0e38f;
#pragma unroll
  for (int j = 0; j < 16; ++j) {
    int i = tid + j * 256;
    if (i < 4000)
#pragma unroll
      for (int k = 0; k < 8; ++k) mx = fmaxf(mx, b2f(d[j][k]));
  }
#pragma unroll
  for (int off = 32; off; off >>= 1) mx = fmaxf(mx, __shfl_xor(mx, off));
  if (lane == 0) red[w] = mx;
  __syncthreads();
  mx = fmaxf(fmaxf(red[0], red[1]), fmaxf(red[2], red[3]));
  __syncthreads();
  float s = 0.f;
#pragma unroll
  for (int j = 0; j < 16; ++j) {
    int i = tid + j * 256;
    if (i < 4000)
#pragma unroll
      for (int k = 0; k < 8; ++k) s += __expf(b2f(d[j][k]) - mx);
  }
#pragma unroll
  for (int off = 32; off; off >>= 1) s += __shfl_xor(s, off);
  if (lane == 0) red[w] = s;
  __syncthreads();
  float c = mx + __logf(red[0] + red[1] + red[2] + red[3]);
  float* op = out + (size_t)row * 32000;
#pragma unroll
  for (int j = 0; j < 16; ++j) {
    int i = tid + j * 256;
    if (i < 4000) {
      f32x4 o0, o1;
#pragma unroll
      for (int k = 0; k < 4; ++k) { o0[k] = b2f(d[j][k]) - c; o1[k] = b2f(d[j][k + 4]) - c; }
      *(f32x4*)(op + i * 8) = o0;
      *(f32x4*)(op + i * 8 + 4) = o1;
    }
  }
}

// ---------- fallback f32 log_softmax ----------
__global__ __launch_bounds__(256) void rowstatk(const float* __restrict__ lp, float* __restrict__ c) {
  int row = blockIdx.x;
  const float4* p = (const float4*)(lp + (size_t)row * 32000);
  int tid = threadIdx.x, lane = tid & 63, w = tid >> 6;
  __shared__ float redm[4], reds[4];
  float mx = -3.0e38f;
  for (int i = tid; i < 8000; i += 256) {
    float4 v = p[i];
    mx = fmaxf(mx, fmaxf(fmaxf(v.x, v.y), fmaxf(v.z, v.w)));
  }
#pragma unroll
  for (int off = 32; off; off >>= 1) mx = fmaxf(mx, __shfl_xor(mx, off));
  if (lane == 0) redm[w] = mx;
  __syncthreads();
  mx = fmaxf(fmaxf(redm[0], redm[1]), fmaxf(redm[2], redm[3]));
  float s = 0.f;
  for (int i = tid; i < 8000; i += 256) {
    float4 v = p[i];
    s += __expf(v.x - mx) + __expf(v.y - mx) + __expf(v.z - mx) + __expf(v.w - mx);
  }
#pragma unroll
  for (int off = 32; off; off >>= 1) s += __shfl_xor(s, off);
  if (lane == 0) reds[w] = s;
  __syncthreads();
  if (tid == 0) c[row] = mx + __logf(reds[0] + reds[1] + reds[2] + reds[3]);
}

__global__ __launch_bounds__(256) void subk(float* __restrict__ lp, const float* __restrict__ c) {
  const long n4 = (long)64 * 32 * 32000 / 4;
  long stride = (long)gridDim.x * 256;
  for (long i = (long)blockIdx.x * 256 + threadIdx.x; i < n4; i += stride) {
    float4 v = ((float4*)lp)[i];
    float cc = c[i / 8000];
    v.x -= cc; v.y -= cc; v.z -= cc; v.w -= cc;
    ((float4*)lp)[i] = v;
  }
}

extern "C" void kernel_launch(void* const* d_in, const int* in_sizes, int n_in, void* d_out, int out_size,
                              void* d_ws, size_t ws_size, hipStream_t stream) {
  (void)in_sizes; (void)n_in; (void)out_size;
  constexpr int B = 64, S = 128, T = 32, H = 1024, V = 32000;

  const float* enc  = (const float*)d_in[0];
  const float* ehid = (const float*)d_in[1];
  const int*   tgt  = (const int*)d_in[2];
  const float* embd = (const float*)d_in[3];
  const float* Wa   = (const float*)d_in[4];
  const float* ba   = (const float*)d_in[5];
  const float* Ua   = (const float*)d_in[6];
  const float* bu   = (const float*)d_in[7];
  const float* Va   = (const float*)d_in[8];
  // d_in[9] = bv: constant shift, cancels in softmax; not needed.
  const float* Wih  = (const float*)d_in[10];
  const float* bih  = (const float*)d_in[11];
  const float* Whh  = (const float*)d_in[12];
  const float* bhh  = (const float*)d_in[13];
  const float* Wout = (const float*)d_in[14];
  const float* bout = (const float*)d_in[15];

  char* wp = (char*)d_ws;
  auto alloc = [&](size_t bytes) {
    char* p = wp;
    wp += (bytes + 255) & ~(size_t)255;
    return p;
  };
  u16* enc_b  = (u16*)alloc((size_t)B * S * H * 2);
  u16* kp_b   = (u16*)alloc((size_t)B * S * H * 2);
  u16* Ua_b   = (u16*)alloc((size_t)H * H * 2);
  u16* W1_b   = (u16*)alloc((size_t)4096 * 1024 * 2);   // [Wa ; Whh]
  u16* Wih1_b = (u16*)alloc((size_t)3072 * 1024 * 2);
  u16* Wih2_b = (u16*)alloc((size_t)3072 * 1024 * 2);
  u16* Wout_b = (u16*)alloc((size_t)V * H * 2);
  u16* emb_b  = (u16*)alloc((size_t)B * T * H * 2);
  u16* hall_b = (u16*)alloc((size_t)T * B * H * 2);
  float* gie  = (float*)alloc((size_t)B * T * 3072 * 4);
  float* qghp = (float*)alloc((size_t)4 * B * 4096 * 4);
  float* scb  = (float*)alloc((size_t)B * S * 4);
  float* gic  = (float*)alloc((size_t)B * 3072 * 4);
  u16* ctx_b  = (u16*)alloc((size_t)B * H * 2);
  u16* hb0    = (u16*)alloc((size_t)B * H * 2);
  u16* hb1    = (u16*)alloc((size_t)B * H * 2);
  float* h_f  = (float*)alloc((size_t)B * H * 4);
  float* rowc = (float*)alloc(2048 * 4);
  size_t base_need = (size_t)(wp - (char*)d_ws);
  u16* encW2 = (u16*)alloc((size_t)B * S * 3072 * 2);   // 50 MB: enc @ Wih2^T
  bool have_w2 = ((size_t)(wp - (char*)d_ws) <= ws_size);
  u16* lg_b = (u16*)alloc((size_t)B * T * V * 2);       // 128 MB: bf16 logits
  bool bflog = ((size_t)(wp - (char*)d_ws) <= ws_size);
  if (base_need > ws_size) return;  // ws too small: fail loud (wrong output)

  float* out_lp = (float*)d_out;
  float* out_hf = out_lp + (size_t)B * T * V;
  float* out_at = out_hf + (size_t)B * H;

  // ---- prep: one fused kernel (conversions, Wih split, emb gather, h init) ----
  u16* Wa_slot = W1_b;
  u16* Whh_slot = W1_b + (size_t)1024 * 1024;
  prepk<<<2048, 256, 0, stream>>>(enc, Ua, Wa, Whh, Wout, Wih, embd, tgt, ehid,
                                  enc_b, Ua_b, Wa_slot, Whh_slot, Wout_b,
                                  Wih1_b, Wih2_b, emb_b, h_f, hb0);

  // keys_proj = enc @ Ua^T + bu -> bf16 (B*S, H); grid 512 = 64m x 8n
  gemm_tile<1><<<512, 256, 0, stream>>>(enc_b, Ua_b, bu, nullptr, kp_b, H, H, 64);
  // gi_emb = emb @ Wih1^T + b_ih -> f32 (B*T, 3072); grid 384 = 16m x 24n
  gemm_tile<0><<<384, 256, 0, stream>>>(emb_b, Wih1_b, bih, gie, nullptr, H, 3072, 16);
  if (have_w2) {
    // encW2 = enc @ Wih2^T -> bf16 (B*S, 3072), no bias; 128x256 tiles, grid 768 = 64m x 12n
    gemm_wide<2, 1><<<768, 256, 0, stream>>>(enc_b, Wih2_b, nullptr, nullptr, encW2, H, 3072, 64);
  }

  // ---- recurrence: 3 kernels/step ----
  for (int t = 0; t < T; ++t) {
    u16* hbR = (t & 1) ? hb1 : hb0;
    u16* hbW = (t & 1) ? hb0 : hb1;
    qkghk<<<1024, 256, 0, stream>>>(hbR, W1_b, qghp);
    scorekq<<<512, 256, 0, stream>>>(qghp, ba, Va, kp_b, scb);
    if (have_w2) {
      wsumgate<<<256, 512, 0, stream>>>(scb, encW2, gie, qghp, bhh, h_f, hbW, hall_b,
                                        out_hf, out_at, t);
    } else {
      smaxctxk<<<256, 256, 0, stream>>>(scb, enc_b, ctx_b, out_at, t);
      gi2w<<<192, 256, 0, stream>>>(ctx_b, Wih2_b, gic);
      gatesq<<<256, 256, 0, stream>>>(gic, gie, qghp, bhh, h_f, hbW, hall_b, out_hf, t);
    }
  }

  // ---- batched logits (128x256 tiles, BK=64) + log_softmax ----
  if (bflog) {
    gemm_wide<1, 0><<<2000, 256, 0, stream>>>(hall_b, Wout_b, bout, nullptr, lg_b, H, V, 16);
    logsoftk<<<2048, 256, 0, stream>>>(lg_b, out_lp);
  } else {
    gemm_wide<0, 0><<<2000, 256, 0, stream>>>(hall_b, Wout_b, bout, out_lp, nullptr, H, V, 16);
    rowstatk<<<2048, 256, 0, stream>>>(out_lp, rowc);
    subk<<<2048, 256, 0, stream>>>(out_lp, rowc);
  }
}

// Round 13
// 1396.439 us; speedup vs baseline: 1.0166x; 1.0166x over previous
//
#include <hip/hip_runtime.h>

// AttnDecoderRNN: B=64, S=128, T=32, H=1024, V=32000
// out = [log_probs (B,T,V) | h_final (1,B,H) | attentions (B,T,S)], all f32.

typedef unsigned short u16;
typedef __bf16 bf16x8 __attribute__((ext_vector_type(8)));
typedef float f32x4 __attribute__((ext_vector_type(4)));
typedef u16 u16x8 __attribute__((ext_vector_type(8)));

#define DEV __device__ __forceinline__

DEV u16 f2b(float f) {               // f32 -> bf16 RNE
  union { float f; unsigned u; } v; v.f = f;
  unsigned r = v.u + 0x7fffu + ((v.u >> 16) & 1u);
  return (u16)(r >> 16);
}
DEV float b2f(u16 b) {
  union { unsigned u; float f; } v; v.u = ((unsigned)b) << 16;
  return v.f;
}
DEV float sigm(float x) { return 1.f / (1.f + __expf(-x)); }
DEV float ftanh(float x) {
  x = fminf(fmaxf(x, -20.f), 20.f);
  float e = __expf(2.f * x);
  return (e - 1.f) / (e + 1.f);
}
DEV void gl16(const void* g, void* l) {  // 16B global -> LDS direct (wave-uniform lds base, +lane*16)
  __builtin_amdgcn_global_load_lds((const __attribute__((address_space(1))) void*)g,
                                   (__attribute__((address_space(3))) void*)l, 16, 0, 0);
}

// ---------- single prep kernel: all conversions + Wih split + emb gather + h init ----------
__global__ __launch_bounds__(256) void prepk(const float* __restrict__ enc, const float* __restrict__ Ua,
                                             const float* __restrict__ Wa, const float* __restrict__ Whh,
                                             const float* __restrict__ Wout, const float* __restrict__ Wih,
                                             const float* __restrict__ embd, const int* __restrict__ tgt,
                                             const float* __restrict__ eh, u16* __restrict__ enc_b,
                                             u16* __restrict__ Ua_b, u16* __restrict__ Wa_b,
                                             u16* __restrict__ Whh_b, u16* __restrict__ Wout_b,
                                             u16* __restrict__ Wih1_b, u16* __restrict__ Wih2_b,
                                             u16* __restrict__ emb_b, float* __restrict__ hf,
                                             u16* __restrict__ hb0) {
  const long q0 = 2097152;            // enc        64*128*1024/4
  const long q1 = q0 + 262144;        // Ua         1024*1024/4
  const long q2 = q1 + 262144;        // Wa
  const long q3 = q2 + 786432;        // Whh        3072*1024/4
  const long q4 = q3 + 8192000;       // Wout       32000*1024/4
  const long q5 = q4 + 1572864;       // Wih split  3072*2048/4
  const long q6 = q5 + 524288;        // emb gather 64*32*1024/4
  const long q7 = q6 + 16384;         // h init     64*1024/4
  long stride = (long)gridDim.x * 256;
  for (long i = (long)blockIdx.x * 256 + threadIdx.x; i < q7; i += stride) {
    if (i < q4) {  // plain f32 -> bf16 copies
      const float* src; u16* dst; long off;
      if (i < q0) { src = enc; dst = enc_b; off = i; }
      else if (i < q1) { src = Ua; dst = Ua_b; off = i - q0; }
      else if (i < q2) { src = Wa; dst = Wa_b; off = i - q1; }
      else if (i < q3) { src = Whh; dst = Whh_b; off = i - q2; }
      else { src = Wout; dst = Wout_b; off = i - q3; }
      float4 v = ((const float4*)src)[off];
      ushort4 o; o.x = f2b(v.x); o.y = f2b(v.y); o.z = f2b(v.z); o.w = f2b(v.w);
      ((ushort4*)dst)[off] = o;
    } else if (i < q5) {  // Wih (3072x2048) -> Wih1 | Wih2
      long off = i - q4;
      long e = off * 4;
      int row = (int)(e >> 11), col = (int)(e & 2047);
      float4 v = ((const float4*)Wih)[off];
      ushort4 o; o.x = f2b(v.x); o.y = f2b(v.y); o.z = f2b(v.z); o.w = f2b(v.w);
      u16* dst = (col < 1024) ? (Wih1_b + (size_t)row * 1024 + col)
                              : (Wih2_b + (size_t)row * 1024 + col - 1024);
      *(ushort4*)dst = o;
    } else if (i < q6) {  // embedding gather (SOS=1 teacher forcing)
      long off = i - q5;
      size_t e = (size_t)off * 4;
      int h = (int)(e & 1023);
      int bt = (int)(e >> 10);
      int b = bt >> 5, t = bt & 31;
      int tok = (t == 0) ? 1 : tgt[b * 32 + t - 1];
      const float* src = embd + (size_t)tok * 1024 + h;
      float4 v = *(const float4*)src;
      ushort4 o; o.x = f2b(v.x); o.y = f2b(v.y); o.z = f2b(v.z); o.w = f2b(v.w);
      *(ushort4*)(emb_b + e) = o;
    } else {  // h init: f32 copy + bf16 copy
      long off = i - q6;
      float4 v = ((const float4*)eh)[off];
      ((float4*)hf)[off] = v;
      ushort4 o; o.x = f2b(v.x); o.y = f2b(v.y); o.z = f2b(v.z); o.w = f2b(v.w);
      ((ushort4*)hb0)[off] = o;
    }
  }
}

// ---------- 128x128-tile bf16 MFMA GEMM (NT: A MxK, B NxK, both K-contig) ----------
// Staging: 4 lanes per row (64B contiguous) + XOR chunk swizzle within the row's 64B
//   (source chunk = (lane&3) ^ ((row>>1)&3)) -> coalescing preserved, LDS read conflict-free.
// MODE 0: f32 C=acc+bias. MODE 1: bf16 C=acc+bias. MODE 2: bf16 C=acc (no bias).
template <int MODE>
__global__ __launch_bounds__(256) void gemm_tile(const u16* __restrict__ A, const u16* __restrict__ Bm,
                                                 const float* __restrict__ bias, float* __restrict__ Cf,
                                                 u16* __restrict__ Cb, int K, int ldc, int nTM) {
  __shared__ __attribute__((aligned(16))) u16 As[128 * 32];
  __shared__ __attribute__((aligned(16))) u16 Bs[128 * 32];
  const int tid = threadIdx.x, lane = tid & 63, w = tid >> 6;
  const int chunk = gridDim.x >> 3, wg = blockIdx.x;
  const int id = (wg & 7) * chunk + (wg >> 3);
  const int m = id % nTM, n = id / nTM;
  const int m0 = m * 128, n0 = n * 128;
  const int wm = w >> 1, wn = w & 1;
  const int l16 = lane & 15, kg = lane >> 4;
  const int srow = lane >> 2;
  const int skk = (((lane & 3) ^ ((srow >> 1) & 3)) * 8);
  const int slot = (kg ^ ((l16 >> 1) & 3)) * 8;

  f32x4 acc[4][4];
#pragma unroll
  for (int i = 0; i < 4; ++i)
#pragma unroll
    for (int j = 0; j < 4; ++j) acc[i][j] = f32x4{0.f, 0.f, 0.f, 0.f};

  for (int k0 = 0; k0 < K; k0 += 32) {
#pragma unroll
    for (int ch = 0; ch < 2; ++ch) {
      int c = w + ch * 4;
      gl16(A + (size_t)(m0 + c * 16 + srow) * K + k0 + skk, &As[c * 512]);
      gl16(Bm + (size_t)(n0 + c * 16 + srow) * K + k0 + skk, &Bs[c * 512]);
    }
    __syncthreads();
    bf16x8 av[4], bv[4];
#pragma unroll
    for (int i = 0; i < 4; ++i) av[i] = *(const bf16x8*)&As[(wm * 4 + i) * 512 + l16 * 32 + slot];
#pragma unroll
    for (int j = 0; j < 4; ++j) bv[j] = *(const bf16x8*)&Bs[(wn * 4 + j) * 512 + l16 * 32 + slot];
#pragma unroll
    for (int i = 0; i < 4; ++i)
#pragma unroll
      for (int j = 0; j < 4; ++j)
        acc[i][j] = __builtin_amdgcn_mfma_f32_16x16x32_bf16(av[i], bv[j], acc[i][j], 0, 0, 0);
    __syncthreads();
  }
#pragma unroll
  for (int i = 0; i < 4; ++i) {
    int rowb = m0 + (wm * 4 + i) * 16 + kg * 4;
#pragma unroll
    for (int j = 0; j < 4; ++j) {
      int col = n0 + (wn * 4 + j) * 16 + l16;
      float bb = (MODE == 2) ? 0.f : bias[col];
#pragma unroll
      for (int r = 0; r < 4; ++r) {
        int row = rowb + r;
        float v = acc[i][j][r] + bb;
        if (MODE == 0) Cf[(size_t)row * ldc + col] = v;
        else Cb[(size_t)row * ldc + col] = f2b(v);
      }
    }
  }
}

// ---------- 128x256-tile bf16 MFMA GEMM, BK=64 (2 panels of 32 per K-step) ----------
// MODE 0: f32+bias, logits row remap. MODE 1: bf16+bias, logits row remap.
// MODE 2: bf16, no bias, plain row-major write (encW2).
// MAP 0: logits 16m x 125n with 80-id supertiles. MAP 1: m = id % nTM, n = id / nTM.
template <int MODE, int MAP>
__global__ __launch_bounds__(256, 2) void gemm_wide(const u16* __restrict__ A, const u16* __restrict__ Bm,
                                                    const float* __restrict__ bias, float* __restrict__ Cf,
                                                    u16* __restrict__ Cb, int K, int ldc, int nTM) {
  __shared__ __attribute__((aligned(16))) u16 As[128 * 64];   // 16 KB
  __shared__ __attribute__((aligned(16))) u16 Bs[256 * 64];   // 32 KB
  const int tid = threadIdx.x, lane = tid & 63, w = tid >> 6;
  const int chunk = gridDim.x >> 3, wg = blockIdx.x;
  const int id = (wg & 7) * chunk + (wg >> 3);
  int m, n;
  if (MAP == 0) { int r_ = id % 80; m = r_ & 15; n = 5 * (id / 80) + (r_ >> 4); }
  else { m = id % nTM; n = id / nTM; }
  const int m0 = m * 128, n0 = n * 256;
  const int wm = w >> 1, wn = w & 1;
  const int l16 = lane & 15, kg = lane >> 4;
  const int srow = lane >> 2;
  const int skk = (((lane & 3) ^ ((srow >> 1) & 3)) * 8);
  const int slot = (kg ^ ((l16 >> 1) & 3)) * 8;

  f32x4 acc[4][8];
#pragma unroll
  for (int i = 0; i < 4; ++i)
#pragma unroll
    for (int j = 0; j < 8; ++j) acc[i][j] = f32x4{0.f, 0.f, 0.f, 0.f};

  for (int k0 = 0; k0 < K; k0 += 64) {
#pragma unroll
    for (int ch = 0; ch < 2; ++ch) {
      int c = w + ch * 4;  // A: 8 chunks of 16 rows, 2 panels each
#pragma unroll
      for (int p = 0; p < 2; ++p)
        gl16(A + (size_t)(m0 + c * 16 + srow) * K + k0 + p * 32 + skk, &As[c * 1024 + p * 512]);
    }
#pragma unroll
    for (int ch = 0; ch < 4; ++ch) {
      int c = w + ch * 4;  // B: 16 chunks of 16 rows, 2 panels each
#pragma unroll
      for (int p = 0; p < 2; ++p)
        gl16(Bm + (size_t)(n0 + c * 16 + srow) * K + k0 + p * 32 + skk, &Bs[c * 1024 + p * 512]);
    }
    __syncthreads();
#pragma unroll
    for (int p = 0; p < 2; ++p) {
      bf16x8 av[4], bv[8];
#pragma unroll
      for (int i = 0; i < 4; ++i)
        av[i] = *(const bf16x8*)&As[(wm * 4 + i) * 1024 + p * 512 + l16 * 32 + slot];
#pragma unroll
      for (int j = 0; j < 8; ++j)
        bv[j] = *(const bf16x8*)&Bs[(wn * 8 + j) * 1024 + p * 512 + l16 * 32 + slot];
#pragma unroll
      for (int i = 0; i < 4; ++i)
#pragma unroll
        for (int j = 0; j < 8; ++j)
          acc[i][j] = __builtin_amdgcn_mfma_f32_16x16x32_bf16(av[i], bv[j], acc[i][j], 0, 0, 0);
    }
    __syncthreads();
  }
#pragma unroll
  for (int i = 0; i < 4; ++i) {
    int rowb = m0 + (wm * 4 + i) * 16 + kg * 4;
#pragma unroll
    for (int j = 0; j < 8; ++j) {
      int col = n0 + (wn * 8 + j) * 16 + l16;
      float bb = (MODE == 2) ? 0.f : bias[col];
#pragma unroll
      for (int r = 0; r < 4; ++r) {
        int row = rowb + r;
        float v = acc[i][j][r] + bb;
        if (MODE == 2) {
          Cb[(size_t)row * ldc + col] = f2b(v);
        } else {
          int b_ = row & 63, t_ = row >> 6;  // hall rows are (t*64+b)
          size_t ro = ((size_t)b_ * 32 + t_) * ldc + col;
          if (MODE == 0) Cf[ro] = v; else Cb[ro] = f2b(v);
        }
      }
    }
  }
}

// ---------- per-step K1: qgh partials = h @ [Wa;Whh]^T, K split by 4. grid 1024 ----------
__global__ __launch_bounds__(256) void qkghk(const u16* __restrict__ hb, const u16* __restrict__ W1,
                                             float* __restrict__ qghp) {
  const int tid = threadIdx.x, lane = tid & 63, w = tid >> 6;
  const int l16 = lane & 15, kg = lane >> 4;
  const int pg = blockIdx.x >> 2, ks = blockIdx.x & 3;
  const u16* ap = hb + (size_t)(w * 16 + l16) * 1024 + ks * 256 + kg * 8;
  const u16* bp = W1 + (size_t)(pg * 16 + l16) * 1024 + ks * 256 + kg * 8;
  f32x4 a = {0.f, 0.f, 0.f, 0.f};
#pragma unroll
  for (int k0 = 0; k0 < 256; k0 += 32)
    a = __builtin_amdgcn_mfma_f32_16x16x32_bf16(*(const bf16x8*)(ap + k0), *(const bf16x8*)(bp + k0),
                                                a, 0, 0, 0);
  const int col = pg * 16 + l16;
#pragma unroll
  for (int r = 0; r < 4; ++r) {
    int b = w * 16 + kg * 4 + r;
    qghp[(size_t)ks * 262144 + b * 4096 + col] = a[r];
  }
}

// ---------- per-step K2: scores. grid 1024 = (b 64) x (s-16th 16); 2 scores/wave ----------
__global__ __launch_bounds__(256) void scorekq(const float* __restrict__ qghp, const float* __restrict__ ba,
                                               const float* __restrict__ Va, const u16* __restrict__ kp,
                                               float* __restrict__ sc) {
  const int b = blockIdx.x >> 4, s16 = blockIdx.x & 15;
  const int tid = threadIdx.x, lane = tid & 63, w = tid >> 6;
  __shared__ float qs[1024], vas[1024];
#pragma unroll
  for (int j = 0; j < 4; ++j) {
    int e = tid + j * 256;
    qs[e] = qghp[b * 4096 + e] + qghp[262144 + b * 4096 + e] + qghp[524288 + b * 4096 + e] +
            qghp[786432 + b * 4096 + e] + ba[e];
    vas[e] = Va[e];
  }
  __syncthreads();
#pragma unroll
  for (int si = 0; si < 2; ++si) {
    int s = s16 * 8 + w * 2 + si;
    const bf16x8* kv = (const bf16x8*)(kp + ((size_t)b * 128 + s) * 1024);
    float a = 0.f;
#pragma unroll
    for (int i2 = 0; i2 < 2; ++i2) {
      int e = lane + 64 * i2;
      bf16x8 k8 = kv[e];
#pragma unroll
      for (int j = 0; j < 8; ++j) a += vas[e * 8 + j] * ftanh(qs[e * 8 + j] + (float)k8[j]);
    }
#pragma unroll
    for (int off = 32; off; off >>= 1) a += __shfl_xor(a, off);
    if (lane == 0) sc[b * 128 + s] = a;  // +bv cancels in softmax
  }
}

// ---------- per-step K3: softmax + encW2 weighted sum + GRU gates, 2 blocks/CU ----------
// grid 512 = (b 64) x (col-eighth 8), 512 threads = 16 col-groups (8 cols, u16x8 loads)
// x 32 s-groups (4 s each). LDS pa[32][3][128] (48 KB -> 2 blocks/CU, 50% occupancy).
// Softmax recomputed per block (cheap); gates tail (tid<128) verbatim round-9 body.
__global__ __launch_bounds__(512, 4) void wsumgate(const float* __restrict__ scb, const u16* __restrict__ encW2,
                                                   const float* __restrict__ gie, const float* __restrict__ qghp,
                                                   const float* __restrict__ bhh, float* __restrict__ hf,
                                                   u16* __restrict__ hbW, u16* __restrict__ hall,
                                                   float* __restrict__ hfin, float* __restrict__ att_out, int t) {
  const int b = blockIdx.x >> 3, ce = blockIdx.x & 7;
  const int tid = threadIdx.x, lane = tid & 63, w = tid >> 6;
  __shared__ float wsm[128];
  __shared__ float pa[32][3][128];
  if (w == 0) {  // softmax over 128 scores (verified pattern)
    float v0 = scb[b * 128 + lane], v1 = scb[b * 128 + 64 + lane];
    float mx = fmaxf(v0, v1);
#pragma unroll
    for (int off = 32; off; off >>= 1) mx = fmaxf(mx, __shfl_xor(mx, off));
    float e0 = __expf(v0 - mx), e1 = __expf(v1 - mx);
    float sm = e0 + e1;
#pragma unroll
    for (int off = 32; off; off >>= 1) sm += __shfl_xor(sm, off);
    float inv = 1.f / sm;
    e0 *= inv; e1 *= inv;
    wsm[lane] = e0; wsm[lane + 64] = e1;
    if (ce == 0) {
      size_t ao = ((size_t)b * 32 + t) * 128;
      att_out[ao + lane] = e0;
      att_out[ao + lane + 64] = e1;
    }
  }
  __syncthreads();
  const int cg8 = tid & 15, sg = tid >> 4;    // col-group (8 cols), s-group (4 s)
  const int colBase = ce * 128 + cg8 * 8;
  float a0[8], a1[8], a2[8];
#pragma unroll
  for (int k = 0; k < 8; ++k) { a0[k] = 0.f; a1[k] = 0.f; a2[k] = 0.f; }
  const u16* ep = encW2 + ((size_t)b * 128 + sg * 4) * 3072 + colBase;
#pragma unroll
  for (int si = 0; si < 4; ++si) {
    float ws = wsm[sg * 4 + si];
    u16x8 v0 = *(const u16x8*)(ep);
    u16x8 v1 = *(const u16x8*)(ep + 1024);
    u16x8 v2 = *(const u16x8*)(ep + 2048);
#pragma unroll
    for (int k = 0; k < 8; ++k) {
      a0[k] += ws * b2f(v0[k]);
      a1[k] += ws * b2f(v1[k]);
      a2[k] += ws * b2f(v2[k]);
    }
    ep += 3072;
  }
  {
    f32x4 t0 = {a0[0], a0[1], a0[2], a0[3]}, t1 = {a0[4], a0[5], a0[6], a0[7]};
    *(f32x4*)&pa[sg][0][cg8 * 8] = t0; *(f32x4*)&pa[sg][0][cg8 * 8 + 4] = t1;
    f32x4 t2 = {a1[0], a1[1], a1[2], a1[3]}, t3 = {a1[4], a1[5], a1[6], a1[7]};
    *(f32x4*)&pa[sg][1][cg8 * 8] = t2; *(f32x4*)&pa[sg][1][cg8 * 8 + 4] = t3;
    f32x4 t4 = {a2[0], a2[1], a2[2], a2[3]}, t5 = {a2[4], a2[5], a2[6], a2[7]};
    *(f32x4*)&pa[sg][2][cg8 * 8] = t4; *(f32x4*)&pa[sg][2][cg8 * 8 + 4] = t5;
  }
  __syncthreads();
  if (tid < 128) {
    float g0 = 0.f, g1 = 0.f, g2 = 0.f;
#pragma unroll
    for (int s2 = 0; s2 < 32; ++s2) {
      g0 += pa[s2][0][tid]; g1 += pa[s2][1][tid]; g2 += pa[s2][2][tid];
    }
    const int c2 = ce * 128 + tid;
    const float* ge = gie + ((size_t)b * 32 + t) * 3072 + c2;   // emb part of gi (+b_ih)
    const float* qg = qghp + (size_t)b * 4096 + 1024 + c2;      // gh partials (W1 rows 1024+)
    float hr = qg[0] + qg[262144] + qg[524288] + qg[786432] + bhh[c2];
    float hz = qg[1024] + qg[1024 + 262144] + qg[1024 + 524288] + qg[1024 + 786432] + bhh[c2 + 1024];
    float hn = qg[2048] + qg[2048 + 262144] + qg[2048 + 524288] + qg[2048 + 786432] + bhh[c2 + 2048];
    float rr = sigm(g0 + ge[0] + hr);
    float zz = sigm(g1 + ge[1024] + hz);
    float nn = ftanh(g2 + ge[2048] + rr * hn);
    const int i = b * 1024 + c2;
    float hp = hf[i];
    float hv = (1.f - zz) * nn + zz * hp;
    hf[i] = hv;
    u16 h16 = f2b(hv);
    hbW[i] = h16;
    hall[((size_t)t * 64 + b) * 1024 + c2] = h16;
    if (t == 31) hfin[i] = hv;
  }
}

// ---------- fallback per-step kernels (used only when encW2 does not fit in ws) ----------
__global__ __launch_bounds__(256) void smaxctxk(const float* __restrict__ sc, const u16* __restrict__ encb,
                                                u16* __restrict__ ctxb, float* __restrict__ att_out, int t) {
  const int b = blockIdx.x >> 2, hq = blockIdx.x & 3;
  const int tid = threadIdx.x, lane = tid & 63, w = tid >> 6;
  __shared__ float wsm[128];
  if (w == 0) {
    float v0 = sc[b * 128 + lane], v1 = sc[b * 128 + 64 + lane];
    float mx = fmaxf(v0, v1);
#pragma unroll
    for (int off = 32; off; off >>= 1) mx = fmaxf(mx, __shfl_xor(mx, off));
    float e0 = __expf(v0 - mx), e1 = __expf(v1 - mx);
    float sm = e0 + e1;
#pragma unroll
    for (int off = 32; off; off >>= 1) sm += __shfl_xor(sm, off);
    float inv = 1.f / sm;
    e0 *= inv; e1 *= inv;
    wsm[lane] = e0; wsm[lane + 64] = e1;
    if (hq == 0) {
      size_t ao = ((size_t)b * 32 + t) * 128;
      att_out[ao + lane] = e0;
      att_out[ao + lane + 64] = e1;
    }
  }
  __syncthreads();
  const int h = hq * 256 + tid;
  const u16* ep = encb + (size_t)b * 131072 + h;
  float c = 0.f;
#pragma unroll 8
  for (int s = 0; s < 128; ++s) c += wsm[s] * b2f(ep[(size_t)s * 1024]);
  ctxb[(size_t)b * 1024 + h] = f2b(c);
}

__global__ __launch_bounds__(256) void gi2w(const u16* __restrict__ ctxb, const u16* __restrict__ Wih2,
                                            float* __restrict__ gic) {
  const int tid = threadIdx.x, lane = tid & 63, w = tid >> 6;
  const int l16 = lane & 15, kg = lane >> 4;
  const int c0 = blockIdx.x * 16;  // grid 192
  const u16* ap = ctxb + (size_t)(w * 16 + l16) * 1024 + kg * 8;
  const u16* bp = Wih2 + (size_t)(c0 + l16) * 1024 + kg * 8;
  f32x4 a0 = {0.f, 0.f, 0.f, 0.f}, a1 = {0.f, 0.f, 0.f, 0.f};
#pragma unroll 4
  for (int k0 = 0; k0 < 1024; k0 += 64) {
    a0 = __builtin_amdgcn_mfma_f32_16x16x32_bf16(*(const bf16x8*)(ap + k0), *(const bf16x8*)(bp + k0),
                                                 a0, 0, 0, 0);
    a1 = __builtin_amdgcn_mfma_f32_16x16x32_bf16(*(const bf16x8*)(ap + k0 + 32),
                                                 *(const bf16x8*)(bp + k0 + 32), a1, 0, 0, 0);
  }
  const int col = c0 + l16;
#pragma unroll
  for (int r = 0; r < 4; ++r) {
    int b = w * 16 + kg * 4 + r;
    gic[(size_t)b * 3072 + col] = a0[r] + a1[r];
  }
}

__global__ __launch_bounds__(256) void gatesq(const float* __restrict__ gic, const float* __restrict__ gie,
                                              const float* __restrict__ qghp, const float* __restrict__ bhh,
                                              float* __restrict__ hf, u16* __restrict__ hbW,
                                              u16* __restrict__ hall, float* __restrict__ hfin, int t) {
  const int i = blockIdx.x * 256 + threadIdx.x;  // 65536 = (b, col)
  const int b = i >> 10, col = i & 1023;
  const float* gi = gic + (size_t)b * 3072 + col;
  const float* ge = gie + ((size_t)b * 32 + t) * 3072 + col;
  const float* qg = qghp + (size_t)b * 4096 + 1024 + col;
  float hr = qg[0] + qg[262144] + qg[524288] + qg[786432] + bhh[col];
  float hz = qg[1024] + qg[1024 + 262144] + qg[1024 + 524288] + qg[1024 + 786432] + bhh[col + 1024];
  float hn = qg[2048] + qg[2048 + 262144] + qg[2048 + 524288] + qg[2048 + 786432] + bhh[col + 2048];
  float rr = sigm(gi[0] + ge[0] + hr);
  float zz = sigm(gi[1024] + ge[1024] + hz);
  float nn = ftanh(gi[2048] + ge[2048] + rr * hn);
  float hp = hf[i];
  float hv = (1.f - zz) * nn + zz * hp;
  hf[i] = hv;
  u16 h16 = f2b(hv);
  hbW[i] = h16;
  hall[((size_t)t * 64 + b) * 1024 + col] = h16;
  if (t == 31) hfin[i] = hv;
}

// ---------- fused log_softmax over bf16 logits ----------
__global__ __launch_bounds__(256) void logsoftk(const u16* __restrict__ lg, float* __restrict__ out) {
  const int row = blockIdx.x, tid = threadIdx.x, lane = tid & 63, w = tid >> 6;
  const u16x8* p = (const u16x8*)(lg + (size_t)row * 32000);
  __shared__ float red[4];
  u16x8 d[16];
#pragma unroll
  for (int j = 0; j < 16; ++j) {
    int i = tid + j * 256;
    if (i < 4000) d[j] = p[i];
  }
  float mx = -3.0e38f;
#pragma unroll
  for (int j = 0; j < 16; ++j) {
    int i = tid + j * 256;
    if (i < 4000)
#pragma unroll
      for (int k = 0; k < 8; ++k) mx = fmaxf(mx, b2f(d[j][k]));
  }
#pragma unroll
  for (int off = 32; off; off >>= 1) mx = fmaxf(mx, __shfl_xor(mx, off));
  if (lane == 0) red[w] = mx;
  __syncthreads();
  mx = fmaxf(fmaxf(red[0], red[1]), fmaxf(red[2], red[3]));
  __syncthreads();
  float s = 0.f;
#pragma unroll
  for (int j = 0; j < 16; ++j) {
    int i = tid + j * 256;
    if (i < 4000)
#pragma unroll
      for (int k = 0; k < 8; ++k) s += __expf(b2f(d[j][k]) - mx);
  }
#pragma unroll
  for (int off = 32; off; off >>= 1) s += __shfl_xor(s, off);
  if (lane == 0) red[w] = s;
  __syncthreads();
  float c = mx + __logf(red[0] + red[1] + red[2] + red[3]);
  float* op = out + (size_t)row * 32000;
#pragma unroll
  for (int j = 0; j < 16; ++j) {
    int i = tid + j * 256;
    if (i < 4000) {
      f32x4 o0, o1;
#pragma unroll
      for (int k = 0; k < 4; ++k) { o0[k] = b2f(d[j][k]) - c; o1[k] = b2f(d[j][k + 4]) - c; }
      *(f32x4*)(op + i * 8) = o0;
      *(f32x4*)(op + i * 8 + 4) = o1;
    }
  }
}

// ---------- fallback f32 log_softmax ----------
__global__ __launch_bounds__(256) void rowstatk(const float* __restrict__ lp, float* __restrict__ c) {
  int row = blockIdx.x;
  const float4* p = (const float4*)(lp + (size_t)row * 32000);
  int tid = threadIdx.x, lane = tid & 63, w = tid >> 6;
  __shared__ float redm[4], reds[4];
  float mx = -3.0e38f;
  for (int i = tid; i < 8000; i += 256) {
    float4 v = p[i];
    mx = fmaxf(mx, fmaxf(fmaxf(v.x, v.y), fmaxf(v.z, v.w)));
  }
#pragma unroll
  for (int off = 32; off; off >>= 1) mx = fmaxf(mx, __shfl_xor(mx, off));
  if (lane == 0) redm[w] = mx;
  __syncthreads();
  mx = fmaxf(fmaxf(redm[0], redm[1]), fmaxf(redm[2], redm[3]));
  float s = 0.f;
  for (int i = tid; i < 8000; i += 256) {
    float4 v = p[i];
    s += __expf(v.x - mx) + __expf(v.y - mx) + __expf(v.z - mx) + __expf(v.w - mx);
  }
#pragma unroll
  for (int off = 32; off; off >>= 1) s += __shfl_xor(s, off);
  if (lane == 0) reds[w] = s;
  __syncthreads();
  if (tid == 0) c[row] = mx + __logf(reds[0] + reds[1] + reds[2] + reds[3]);
}

__global__ __launch_bounds__(256) void subk(float* __restrict__ lp, const float* __restrict__ c) {
  const long n4 = (long)64 * 32 * 32000 / 4;
  long stride = (long)gridDim.x * 256;
  for (long i = (long)blockIdx.x * 256 + threadIdx.x; i < n4; i += stride) {
    float4 v = ((float4*)lp)[i];
    float cc = c[i / 8000];
    v.x -= cc; v.y -= cc; v.z -= cc; v.w -= cc;
    ((float4*)lp)[i] = v;
  }
}

extern "C" void kernel_launch(void* const* d_in, const int* in_sizes, int n_in, void* d_out, int out_size,
                              void* d_ws, size_t ws_size, hipStream_t stream) {
  (void)in_sizes; (void)n_in; (void)out_size;
  constexpr int B = 64, S = 128, T = 32, H = 1024, V = 32000;

  const float* enc  = (const float*)d_in[0];
  const float* ehid = (const float*)d_in[1];
  const int*   tgt  = (const int*)d_in[2];
  const float* embd = (const float*)d_in[3];
  const float* Wa   = (const float*)d_in[4];
  const float* ba   = (const float*)d_in[5];
  const float* Ua   = (const float*)d_in[6];
  const float* bu   = (const float*)d_in[7];
  const float* Va   = (const float*)d_in[8];
  // d_in[9] = bv: constant shift, cancels in softmax; not needed.
  const float* Wih  = (const float*)d_in[10];
  const float* bih  = (const float*)d_in[11];
  const float* Whh  = (const float*)d_in[12];
  const float* bhh  = (const float*)d_in[13];
  const float* Wout = (const float*)d_in[14];
  const float* bout = (const float*)d_in[15];

  char* wp = (char*)d_ws;
  auto alloc = [&](size_t bytes) {
    char* p = wp;
    wp += (bytes + 255) & ~(size_t)255;
    return p;
  };
  u16* enc_b  = (u16*)alloc((size_t)B * S * H * 2);
  u16* kp_b   = (u16*)alloc((size_t)B * S * H * 2);
  u16* Ua_b   = (u16*)alloc((size_t)H * H * 2);
  u16* W1_b   = (u16*)alloc((size_t)4096 * 1024 * 2);   // [Wa ; Whh]
  u16* Wih1_b = (u16*)alloc((size_t)3072 * 1024 * 2);
  u16* Wih2_b = (u16*)alloc((size_t)3072 * 1024 * 2);
  u16* Wout_b = (u16*)alloc((size_t)V * H * 2);
  u16* emb_b  = (u16*)alloc((size_t)B * T * H * 2);
  u16* hall_b = (u16*)alloc((size_t)T * B * H * 2);
  float* gie  = (float*)alloc((size_t)B * T * 3072 * 4);
  float* qghp = (float*)alloc((size_t)4 * B * 4096 * 4);
  float* scb  = (float*)alloc((size_t)B * S * 4);
  float* gic  = (float*)alloc((size_t)B * 3072 * 4);
  u16* ctx_b  = (u16*)alloc((size_t)B * H * 2);
  u16* hb0    = (u16*)alloc((size_t)B * H * 2);
  u16* hb1    = (u16*)alloc((size_t)B * H * 2);
  float* h_f  = (float*)alloc((size_t)B * H * 4);
  float* rowc = (float*)alloc(2048 * 4);
  size_t base_need = (size_t)(wp - (char*)d_ws);
  u16* encW2 = (u16*)alloc((size_t)B * S * 3072 * 2);   // 50 MB: enc @ Wih2^T
  bool have_w2 = ((size_t)(wp - (char*)d_ws) <= ws_size);
  u16* lg_b = (u16*)alloc((size_t)B * T * V * 2);       // 128 MB: bf16 logits
  bool bflog = ((size_t)(wp - (char*)d_ws) <= ws_size);
  if (base_need > ws_size) return;  // ws too small: fail loud (wrong output)

  float* out_lp = (float*)d_out;
  float* out_hf = out_lp + (size_t)B * T * V;
  float* out_at = out_hf + (size_t)B * H;

  // ---- prep: one fused kernel (conversions, Wih split, emb gather, h init) ----
  u16* Wa_slot = W1_b;
  u16* Whh_slot = W1_b + (size_t)1024 * 1024;
  prepk<<<2048, 256, 0, stream>>>(enc, Ua, Wa, Whh, Wout, Wih, embd, tgt, ehid,
                                  enc_b, Ua_b, Wa_slot, Whh_slot, Wout_b,
                                  Wih1_b, Wih2_b, emb_b, h_f, hb0);

  // keys_proj = enc @ Ua^T + bu -> bf16 (B*S, H); grid 512 = 64m x 8n
  gemm_tile<1><<<512, 256, 0, stream>>>(enc_b, Ua_b, bu, nullptr, kp_b, H, H, 64);
  // gi_emb = emb @ Wih1^T + b_ih -> f32 (B*T, 3072); grid 384 = 16m x 24n
  gemm_tile<0><<<384, 256, 0, stream>>>(emb_b, Wih1_b, bih, gie, nullptr, H, 3072, 16);
  if (have_w2) {
    // encW2 = enc @ Wih2^T -> bf16 (B*S, 3072), no bias; 128x256 tiles, grid 768 = 64m x 12n
    gemm_wide<2, 1><<<768, 256, 0, stream>>>(enc_b, Wih2_b, nullptr, nullptr, encW2, H, 3072, 64);
  }

  // ---- recurrence: 3 kernels/step ----
  for (int t = 0; t < T; ++t) {
    u16* hbR = (t & 1) ? hb1 : hb0;
    u16* hbW = (t & 1) ? hb0 : hb1;
    qkghk<<<1024, 256, 0, stream>>>(hbR, W1_b, qghp);
    scorekq<<<1024, 256, 0, stream>>>(qghp, ba, Va, kp_b, scb);
    if (have_w2) {
      wsumgate<<<512, 512, 0, stream>>>(scb, encW2, gie, qghp, bhh, h_f, hbW, hall_b,
                                        out_hf, out_at, t);
    } else {
      smaxctxk<<<256, 256, 0, stream>>>(scb, enc_b, ctx_b, out_at, t);
      gi2w<<<192, 256, 0, stream>>>(ctx_b, Wih2_b, gic);
      gatesq<<<256, 256, 0, stream>>>(gic, gie, qghp, bhh, h_f, hbW, hall_b, out_hf, t);
    }
  }

  // ---- batched logits (128x256 tiles, BK=64) + log_softmax ----
  if (bflog) {
    gemm_wide<1, 0><<<2000, 256, 0, stream>>>(hall_b, Wout_b, bout, nullptr, lg_b, H, V, 16);
    logsoftk<<<2048, 256, 0, stream>>>(lg_b, out_lp);
  } else {
    gemm_wide<0, 0><<<2000, 256, 0, stream>>>(hall_b, Wout_b, bout, out_lp, nullptr, H, V, 16);
    rowstatk<<<2048, 256, 0, stream>>>(out_lp, rowc);
    subk<<<2048, 256, 0, stream>>>(out_lp, rowc);
  }
}